// Round 1
// baseline (85562.732 us; speedup 1.0000x reference)
//
#include <hip/hip_runtime.h>
#include <hip/hip_bf16.h>

#define T_STEPS 2048
#define NN 4000
#define N_IN 32
#define N_OUT 32
#define NEXT 4032          // N_IN + NN
#define NWG 250            // workgroups in persistent scan kernel
#define ROWS_PER_WG 16     // 250*16 = 4000
#define TPB 256
#define MAX_NNZ 7680       // per-WG LDS nnz capacity (mean 6400, sigma 76 -> 16.9 sigma headroom)
#define LEAK 0.99f

// ---------------------------------------------------------------------------
// drive[t][n] = b + sum_k X[t][k]*W_in[n][k] + sum_k y[t][k]*W_fb[n][k]
// grid: (16, 2048), block 256
// ---------------------------------------------------------------------------
__global__ void drive_kernel(const float* __restrict__ X, const float* __restrict__ y,
                             const float* __restrict__ W_in, const float* __restrict__ W_fb,
                             const float* __restrict__ b, float* __restrict__ drive) {
  __shared__ float s_x[N_IN];
  __shared__ float s_y[N_OUT];
  const int t = blockIdx.y;
  const int tid = threadIdx.x;
  if (tid < N_IN) s_x[tid] = X[t * N_IN + tid];
  else if (tid < N_IN + N_OUT) s_y[tid - N_IN] = y[t * N_OUT + (tid - N_IN)];
  __syncthreads();
  const int n = blockIdx.x * TPB + tid;
  if (n < NN) {
    float acc = b[0];
    const float* wi = W_in + (size_t)n * N_IN;
    const float* wf = W_fb + (size_t)n * N_OUT;
#pragma unroll
    for (int k = 0; k < N_IN; ++k) acc += s_x[k] * wi[k];
#pragma unroll
    for (int k = 0; k < N_OUT; ++k) acc += s_y[k] * wf[k];
    drive[(size_t)t * NN + n] = acc;
  }
}

// ---------------------------------------------------------------------------
// WoT[k][o] = W_out[o][k]   (k < 4032, o < 32)
// ---------------------------------------------------------------------------
__global__ void transpose_wout_kernel(const float* __restrict__ W_out, float* __restrict__ WoT) {
  const int idx = blockIdx.x * TPB + threadIdx.x;
  if (idx < N_OUT * NEXT) {
    const int o = idx / NEXT;
    const int k = idx % NEXT;
    WoT[k * N_OUT + o] = W_out[idx];
  }
}

// ---------------------------------------------------------------------------
// Persistent scan kernel. 250 WGs x 256 threads, 1 WG per CU (LDS-bound).
// Each WG: builds CSR slice of its 16 rows in LDS (W_res read exactly once),
// then iterates T steps with a device-wide counter barrier between steps.
// ---------------------------------------------------------------------------
__global__ __launch_bounds__(TPB, 1) void esn_scan_kernel(
    const float* __restrict__ W_res,
    const float* __restrict__ drive,
    float* __restrict__ states,
    unsigned* __restrict__ bar) {
  __shared__ float s_vals[MAX_NNZ];
  __shared__ unsigned short s_cols[MAX_NNZ];
  __shared__ float s_h[NN];
  __shared__ unsigned s_cnt[ROWS_PER_WG];
  __shared__ unsigned s_start[ROWS_PER_WG + 1];

  const int tid = threadIdx.x;
  const int wg = blockIdx.x;
  const int row0 = wg * ROWS_PER_WG;
  const int wave = tid >> 6;
  const int lane = tid & 63;

  // ---- pass 1: count nonzeros per row (wave-per-row, ballot+popc) ----
  for (int rl = 0; rl < 4; ++rl) {
    const int r = wave * 4 + rl;
    const float* wrow = W_res + (size_t)(row0 + r) * NN;
    unsigned cnt = 0;
    for (int c0 = 0; c0 < NN; c0 += 64) {
      const int c = c0 + lane;
      const float w = (c < NN) ? wrow[c] : 0.0f;
      cnt += (unsigned)__popcll(__ballot(w != 0.0f));
    }
    if (lane == 0) s_cnt[r] = cnt;
  }
  __syncthreads();
  if (tid == 0) {
    unsigned acc = 0;
    for (int r = 0; r < ROWS_PER_WG; ++r) { s_start[r] = acc; acc += s_cnt[r]; }
    s_start[ROWS_PER_WG] = acc;
  }
  __syncthreads();

  // ---- pass 2: ordered fill (deterministic: ballot-prefix within wave) ----
  for (int rl = 0; rl < 4; ++rl) {
    const int r = wave * 4 + rl;
    const float* wrow = W_res + (size_t)(row0 + r) * NN;
    unsigned off = s_start[r];
    for (int c0 = 0; c0 < NN; c0 += 64) {
      const int c = c0 + lane;
      const float w = (c < NN) ? wrow[c] : 0.0f;
      const unsigned long long m = __ballot(w != 0.0f);
      if (w != 0.0f) {
        const unsigned pos = off + (unsigned)__popcll(m & ((1ULL << lane) - 1ULL));
        if (pos < MAX_NNZ) { s_vals[pos] = w; s_cols[pos] = (unsigned short)c; }
      }
      off += (unsigned)__popcll(m);
    }
  }

  // h_0 = 0
  for (int i = tid; i < NN; i += TPB) s_h[i] = 0.0f;
  __syncthreads();

  const int r = tid >> 4;       // row within slice (0..15)
  const int l16 = tid & 15;     // lane within row-group
  const int myrow = row0 + r;
  const unsigned kbeg = s_start[r];
  const unsigned kend = s_start[r + 1];

  for (int t = 0; t < T_STEPS; ++t) {
    // independent load, issued early to overlap with LDS gather
    const float dv = (l16 == 0) ? drive[(size_t)t * NN + myrow] : 0.0f;

    float acc = 0.0f;
    for (unsigned k = kbeg + (unsigned)l16; k < kend; k += 16)
      acc += s_vals[k] * s_h[s_cols[k]];
    acc += __shfl_xor(acc, 1);
    acc += __shfl_xor(acc, 2);
    acc += __shfl_xor(acc, 4);
    acc += __shfl_xor(acc, 8);

    if (l16 == 0) {
      const float pre = acc + dv;   // b already folded into drive
      const float hn = LEAK * tanhf(pre) + (1.0f - LEAK) * s_h[myrow];
      states[(size_t)t * NN + myrow] = hn;
    }
    if (t == T_STEPS - 1) break;

    // ---- device-wide barrier (monotone counter, release/acquire) ----
    __threadfence();        // release my states[t] stores (all threads)
    __syncthreads();
    if (tid == 0) {
      __hip_atomic_fetch_add(bar, 1u, __ATOMIC_ACQ_REL, __HIP_MEMORY_SCOPE_AGENT);
      const unsigned target = (unsigned)(t + 1) * NWG;
      while (__hip_atomic_load(bar, __ATOMIC_ACQUIRE, __HIP_MEMORY_SCOPE_AGENT) < target)
        __builtin_amdgcn_s_sleep(1);
    }
    __syncthreads();
    __threadfence();        // acquire: invalidate stale cached h

    // re-stage h_{t+1} = states[t][:] into LDS (coalesced float4)
    const float4* src4 = (const float4*)(states + (size_t)t * NN);
    float4* dst4 = (float4*)s_h;
    for (int i = tid; i < NN / 4; i += TPB) dst4[i] = src4[i];
    __syncthreads();
  }
}

// ---------------------------------------------------------------------------
// out[t][o] = sum_k X[t][k]*WoT[k][o] + sum_j states[t][j]*WoT[32+j][o]
// block 256 = 8 t x 32 o; grid 256
// ---------------------------------------------------------------------------
__global__ void out_kernel(const float* __restrict__ X, const float* __restrict__ states,
                           const float* __restrict__ WoT, float* __restrict__ out) {
  const int o = threadIdx.x & 31;
  const int tl = threadIdx.x >> 5;
  const int t = blockIdx.x * 8 + tl;
  float acc = 0.0f;
  const float* xrow = X + (size_t)t * N_IN;
#pragma unroll
  for (int k = 0; k < N_IN; ++k) acc += xrow[k] * WoT[k * N_OUT + o];
  const float* srow = states + (size_t)t * NN;
  for (int j = 0; j < NN; ++j) acc += srow[j] * WoT[(N_IN + j) * N_OUT + o];
  out[(size_t)t * N_OUT + o] = acc;
}

// ---------------------------------------------------------------------------
extern "C" void kernel_launch(void* const* d_in, const int* in_sizes, int n_in,
                              void* d_out, int out_size, void* d_ws, size_t ws_size,
                              hipStream_t stream) {
  const float* X     = (const float*)d_in[0];
  const float* y     = (const float*)d_in[1];
  const float* W_in  = (const float*)d_in[2];
  const float* W_res = (const float*)d_in[3];
  const float* W_fb  = (const float*)d_in[4];
  const float* W_out = (const float*)d_in[5];
  const float* b     = (const float*)d_in[6];
  float* out = (float*)d_out;

  // workspace layout (floats):
  //   drive : [2048][4000]          at 0            (8,192,000)
  //   states: [2048][4000]          at 8,192,000    (8,192,000)
  //   WoT   : [4032][32]            at 16,384,000   (129,024)
  //   bar   : unsigned counter      at 16,513,024   (aligned, 64B zeroed)
  float* ws = (float*)d_ws;
  float* drive  = ws;
  float* states = ws + 8192000;
  float* WoT    = ws + 16384000;
  unsigned* bar = (unsigned*)(ws + 16513024);

  hipMemsetAsync(bar, 0, 64, stream);
  drive_kernel<<<dim3(16, T_STEPS), TPB, 0, stream>>>(X, y, W_in, W_fb, b, drive);
  transpose_wout_kernel<<<(N_OUT * NEXT + TPB - 1) / TPB, TPB, 0, stream>>>(W_out, WoT);
  esn_scan_kernel<<<NWG, TPB, 0, stream>>>(W_res, drive, states, bar);
  out_kernel<<<T_STEPS / 8, TPB, 0, stream>>>(X, states, WoT, out);
}

// Round 2
// 53871.259 us; speedup vs baseline: 1.5883x; 1.5883x over previous
//
#include <hip/hip_runtime.h>
#include <hip/hip_bf16.h>

#define T_STEPS 2048
#define NN 4000
#define N_IN 32
#define N_OUT 32
#define NEXT 4032          // N_IN + NN
#define NWG 250            // workgroups in persistent scan kernel
#define ROWS_PER_WG 16     // 250*16 = 4000
#define TPB 256
#define MAX_NNZ 7680       // per-WG LDS nnz capacity (mean 6400, sigma 76)
#define LEAK 0.99f
#define FLAG_STRIDE 16     // u32s = 64B per flag line (own cacheline per WG)

// ---------------------------------------------------------------------------
// drive[t][n] = b + sum_k X[t][k]*W_in[n][k] + sum_k y[t][k]*W_fb[n][k]
// ---------------------------------------------------------------------------
__global__ void drive_kernel(const float* __restrict__ X, const float* __restrict__ y,
                             const float* __restrict__ W_in, const float* __restrict__ W_fb,
                             const float* __restrict__ b, float* __restrict__ drive) {
  __shared__ float s_x[N_IN];
  __shared__ float s_y[N_OUT];
  const int t = blockIdx.y;
  const int tid = threadIdx.x;
  if (tid < N_IN) s_x[tid] = X[t * N_IN + tid];
  else if (tid < N_IN + N_OUT) s_y[tid - N_IN] = y[t * N_OUT + (tid - N_IN)];
  __syncthreads();
  const int n = blockIdx.x * TPB + tid;
  if (n < NN) {
    float acc = b[0];
    const float* wi = W_in + (size_t)n * N_IN;
    const float* wf = W_fb + (size_t)n * N_OUT;
#pragma unroll
    for (int k = 0; k < N_IN; ++k) acc += s_x[k] * wi[k];
#pragma unroll
    for (int k = 0; k < N_OUT; ++k) acc += s_y[k] * wf[k];
    drive[(size_t)t * NN + n] = acc;
  }
}

// ---------------------------------------------------------------------------
__global__ void transpose_wout_kernel(const float* __restrict__ W_out, float* __restrict__ WoT) {
  const int idx = blockIdx.x * TPB + threadIdx.x;
  if (idx < N_OUT * NEXT) {
    const int o = idx / NEXT;
    const int k = idx % NEXT;
    WoT[k * N_OUT + o] = W_out[idx];
  }
}

// ---------------------------------------------------------------------------
// Persistent scan kernel. 250 WGs x 256 threads, 1 WG/CU.
// CSR slice of 16 rows packed {val,col} in LDS; distributed-flag barrier.
// ---------------------------------------------------------------------------
__global__ __launch_bounds__(TPB, 1) void esn_scan_kernel(
    const float* __restrict__ W_res,
    const float* __restrict__ drive,
    float* __restrict__ states,
    unsigned* __restrict__ flags) {
  __shared__ float2 s_pk[MAX_NNZ];          // {val, col bits} : one b64 per nnz
  __shared__ float s_h[NN];
  __shared__ unsigned s_cnt[ROWS_PER_WG];
  __shared__ unsigned s_start[ROWS_PER_WG + 1];

  const int tid = threadIdx.x;
  const int wg = blockIdx.x;
  const int row0 = wg * ROWS_PER_WG;
  const int wave = tid >> 6;
  const int lane = tid & 63;

  // ---- pass 1: count nonzeros per row ----
  for (int rl = 0; rl < 4; ++rl) {
    const int r = wave * 4 + rl;
    const float* wrow = W_res + (size_t)(row0 + r) * NN;
    unsigned cnt = 0;
    for (int c0 = 0; c0 < NN; c0 += 64) {
      const int c = c0 + lane;
      const float w = (c < NN) ? wrow[c] : 0.0f;
      cnt += (unsigned)__popcll(__ballot(w != 0.0f));
    }
    if (lane == 0) s_cnt[r] = cnt;
  }
  __syncthreads();
  if (tid == 0) {
    unsigned acc = 0;
    for (int r = 0; r < ROWS_PER_WG; ++r) { s_start[r] = acc; acc += s_cnt[r]; }
    s_start[ROWS_PER_WG] = acc;
  }
  __syncthreads();

  // ---- pass 2: ordered fill, packed {val, col} ----
  for (int rl = 0; rl < 4; ++rl) {
    const int r = wave * 4 + rl;
    const float* wrow = W_res + (size_t)(row0 + r) * NN;
    unsigned off = s_start[r];
    for (int c0 = 0; c0 < NN; c0 += 64) {
      const int c = c0 + lane;
      const float w = (c < NN) ? wrow[c] : 0.0f;
      const unsigned long long m = __ballot(w != 0.0f);
      if (w != 0.0f) {
        const unsigned pos = off + (unsigned)__popcll(m & ((1ULL << lane) - 1ULL));
        if (pos < MAX_NNZ) s_pk[pos] = make_float2(w, __uint_as_float((unsigned)c));
      }
      off += (unsigned)__popcll(m);
    }
  }

  for (int i = tid; i < NN; i += TPB) s_h[i] = 0.0f;   // h_0 = 0
  __syncthreads();

  const int r = tid >> 4;       // row within slice (0..15)
  const int l16 = tid & 15;     // lane within row-group
  const int myrow = row0 + r;
  const unsigned kbeg = s_start[r];
  const unsigned kend = s_start[r + 1];
  unsigned* const myflag = flags + wg * FLAG_STRIDE;

  float dv = (l16 == 0) ? drive[myrow] : 0.0f;   // drive for t=0

  for (int t = 0; t < T_STEPS; ++t) {
    // ---- gather: 2-way unrolled, 2 LDS instrs per nnz ----
    float acc0 = 0.0f, acc1 = 0.0f;
    unsigned k = kbeg + (unsigned)l16;
    for (; k + 16 < kend; k += 32) {
      const float2 p0 = s_pk[k];
      const float2 p1 = s_pk[k + 16];
      acc0 += p0.x * s_h[__float_as_uint(p0.y)];
      acc1 += p1.x * s_h[__float_as_uint(p1.y)];
    }
    if (k < kend) { const float2 p = s_pk[k]; acc0 += p.x * s_h[__float_as_uint(p.y)]; }
    float acc = acc0 + acc1;
    acc += __shfl_xor(acc, 1);
    acc += __shfl_xor(acc, 2);
    acc += __shfl_xor(acc, 4);
    acc += __shfl_xor(acc, 8);

    // prefetch next step's drive (independent of barrier) to hide L3 latency
    const float dv_next = (l16 == 0 && t + 1 < T_STEPS)
                              ? drive[(size_t)(t + 1) * NN + myrow] : 0.0f;

    if (l16 == 0) {
      const float hn = LEAK * tanhf(acc + dv) + (1.0f - LEAK) * s_h[myrow];
      states[(size_t)t * NN + myrow] = hn;
    }
    dv = dv_next;
    if (t == T_STEPS - 1) break;

    // ---- distributed flag barrier ----
    __syncthreads();                       // all 16 row-writes of this WG done
    if (tid == 0) {
      __threadfence();                     // release: flush states[t] stores
      __hip_atomic_store(myflag, (unsigned)(t + 1), __ATOMIC_RELEASE,
                         __HIP_MEMORY_SCOPE_AGENT);
    }
    if (tid < NWG) {
      const unsigned tgt = (unsigned)(t + 1);
      while (__hip_atomic_load(flags + tid * FLAG_STRIDE, __ATOMIC_RELAXED,
                               __HIP_MEMORY_SCOPE_AGENT) < tgt)
        __builtin_amdgcn_s_sleep(1);
    }
    __syncthreads();
    __threadfence();                       // acquire: invalidate stale caches

    // ---- re-stage h_{t+1} = states[t][:] into LDS ----
    const float4* src4 = (const float4*)(states + (size_t)t * NN);
    float4* dst4 = (float4*)s_h;
    for (int i = tid; i < NN / 4; i += TPB) dst4[i] = src4[i];
    __syncthreads();
  }
}

// ---------------------------------------------------------------------------
__global__ void out_kernel(const float* __restrict__ X, const float* __restrict__ states,
                           const float* __restrict__ WoT, float* __restrict__ out) {
  const int o = threadIdx.x & 31;
  const int tl = threadIdx.x >> 5;
  const int t = blockIdx.x * 8 + tl;
  float acc = 0.0f;
  const float* xrow = X + (size_t)t * N_IN;
#pragma unroll
  for (int k = 0; k < N_IN; ++k) acc += xrow[k] * WoT[k * N_OUT + o];
  const float* srow = states + (size_t)t * NN;
  for (int j = 0; j < NN; ++j) acc += srow[j] * WoT[(N_IN + j) * N_OUT + o];
  out[(size_t)t * N_OUT + o] = acc;
}

// ---------------------------------------------------------------------------
extern "C" void kernel_launch(void* const* d_in, const int* in_sizes, int n_in,
                              void* d_out, int out_size, void* d_ws, size_t ws_size,
                              hipStream_t stream) {
  const float* X     = (const float*)d_in[0];
  const float* y     = (const float*)d_in[1];
  const float* W_in  = (const float*)d_in[2];
  const float* W_res = (const float*)d_in[3];
  const float* W_fb  = (const float*)d_in[4];
  const float* W_out = (const float*)d_in[5];
  const float* b     = (const float*)d_in[6];
  float* out = (float*)d_out;

  // workspace layout (floats):
  //   drive : [2048][4000]   at 0             (8,192,000)
  //   states: [2048][4000]   at 8,192,000     (8,192,000)
  //   WoT   : [4032][32]     at 16,384,000    (129,024)
  //   flags : 250 x 64B      at 16,513,024    (4,000 u32)
  float* ws = (float*)d_ws;
  float* drive  = ws;
  float* states = ws + 8192000;
  float* WoT    = ws + 16384000;
  unsigned* flags = (unsigned*)(ws + 16513024);

  hipMemsetAsync(flags, 0, NWG * FLAG_STRIDE * sizeof(unsigned), stream);
  drive_kernel<<<dim3(16, T_STEPS), TPB, 0, stream>>>(X, y, W_in, W_fb, b, drive);
  transpose_wout_kernel<<<(N_OUT * NEXT + TPB - 1) / TPB, TPB, 0, stream>>>(W_out, WoT);
  esn_scan_kernel<<<NWG, TPB, 0, stream>>>(W_res, drive, states, flags);
  out_kernel<<<T_STEPS / 8, TPB, 0, stream>>>(X, states, WoT, out);
}

// Round 3
// 47111.926 us; speedup vs baseline: 1.8162x; 1.1435x over previous
//
#include <hip/hip_runtime.h>
#include <hip/hip_bf16.h>

#define T_STEPS 2048
#define NN 4000
#define N_IN 32
#define N_OUT 32
#define NEXT 4032          // N_IN + NN
#define NWG 250            // workgroups in persistent scan kernel
#define ROWS_PER_WG 16     // 250*16 = 4000
#define TPB 256
#define MAX_NNZ 7680       // per-WG LDS nnz capacity (mean 6400, sigma 76)
#define LEAK 0.99f
#define TAG_STRIDE 16      // u32s = 64B per tag (own cacheline per WG per parity)

// ---------------------------------------------------------------------------
// drive[t][n] = b + sum_k X[t][k]*W_in[n][k] + sum_k y[t][k]*W_fb[n][k]
// ---------------------------------------------------------------------------
__global__ void drive_kernel(const float* __restrict__ X, const float* __restrict__ y,
                             const float* __restrict__ W_in, const float* __restrict__ W_fb,
                             const float* __restrict__ b, float* __restrict__ drive) {
  __shared__ float s_x[N_IN];
  __shared__ float s_y[N_OUT];
  const int t = blockIdx.y;
  const int tid = threadIdx.x;
  if (tid < N_IN) s_x[tid] = X[t * N_IN + tid];
  else if (tid < N_IN + N_OUT) s_y[tid - N_IN] = y[t * N_OUT + (tid - N_IN)];
  __syncthreads();
  const int n = blockIdx.x * TPB + tid;
  if (n < NN) {
    float acc = b[0];
    const float* wi = W_in + (size_t)n * N_IN;
    const float* wf = W_fb + (size_t)n * N_OUT;
#pragma unroll
    for (int k = 0; k < N_IN; ++k) acc += s_x[k] * wi[k];
#pragma unroll
    for (int k = 0; k < N_OUT; ++k) acc += s_y[k] * wf[k];
    drive[(size_t)t * NN + n] = acc;
  }
}

// ---------------------------------------------------------------------------
__global__ void transpose_wout_kernel(const float* __restrict__ W_out, float* __restrict__ WoT) {
  const int idx = blockIdx.x * TPB + threadIdx.x;
  if (idx < N_OUT * NEXT) {
    const int o = idx / NEXT;
    const int k = idx % NEXT;
    WoT[k * N_OUT + o] = W_out[idx];
  }
}

// ---------------------------------------------------------------------------
// Persistent scan kernel. 250 WGs x 256 threads.
// CSR slice of 16 rows packed {val,col} in LDS.
// Data-carrying handshake per step: each WG publishes 16 h values (64B) via
// agent-scope write-through stores + release tag; consumers spin per-producer
// then pull all 250 records into LDS after one acquire fence. Double-buffered
// by step parity.
// ---------------------------------------------------------------------------
__global__ __launch_bounds__(TPB, 1) void esn_scan_kernel(
    const float* __restrict__ W_res,
    const float* __restrict__ drive,
    float* __restrict__ states,
    unsigned* __restrict__ tags,    // [2][NWG][TAG_STRIDE]
    float* __restrict__ rdata) {    // [2][NWG][16]
  __shared__ float2 s_pk[MAX_NNZ];          // {val, col bits} : one b64 per nnz
  __shared__ float s_h[NN];
  __shared__ unsigned s_cnt[ROWS_PER_WG];
  __shared__ unsigned s_start[ROWS_PER_WG + 1];

  const int tid = threadIdx.x;
  const int wg = blockIdx.x;
  const int row0 = wg * ROWS_PER_WG;
  const int wave = tid >> 6;
  const int lane = tid & 63;

  // ---- pass 1: count nonzeros per row ----
  for (int rl = 0; rl < 4; ++rl) {
    const int r = wave * 4 + rl;
    const float* wrow = W_res + (size_t)(row0 + r) * NN;
    unsigned cnt = 0;
    for (int c0 = 0; c0 < NN; c0 += 64) {
      const int c = c0 + lane;
      const float w = (c < NN) ? wrow[c] : 0.0f;
      cnt += (unsigned)__popcll(__ballot(w != 0.0f));
    }
    if (lane == 0) s_cnt[r] = cnt;
  }
  __syncthreads();
  if (tid == 0) {
    unsigned acc = 0;
    for (int r = 0; r < ROWS_PER_WG; ++r) { s_start[r] = acc; acc += s_cnt[r]; }
    s_start[ROWS_PER_WG] = acc;
  }
  __syncthreads();

  // ---- pass 2: ordered fill, packed {val, col} ----
  for (int rl = 0; rl < 4; ++rl) {
    const int r = wave * 4 + rl;
    const float* wrow = W_res + (size_t)(row0 + r) * NN;
    unsigned off = s_start[r];
    for (int c0 = 0; c0 < NN; c0 += 64) {
      const int c = c0 + lane;
      const float w = (c < NN) ? wrow[c] : 0.0f;
      const unsigned long long m = __ballot(w != 0.0f);
      if (w != 0.0f) {
        const unsigned pos = off + (unsigned)__popcll(m & ((1ULL << lane) - 1ULL));
        if (pos < MAX_NNZ) s_pk[pos] = make_float2(w, __uint_as_float((unsigned)c));
      }
      off += (unsigned)__popcll(m);
    }
  }

  for (int i = tid; i < NN; i += TPB) s_h[i] = 0.0f;   // h_0 = 0
  __syncthreads();

  const int r = tid >> 4;       // row within slice (0..15)
  const int l16 = tid & 15;     // lane within row-group
  const int myrow = row0 + r;
  const unsigned kbeg = s_start[r];
  const unsigned kend = s_start[r + 1];

  float dv = (l16 == 0) ? drive[myrow] : 0.0f;   // drive for t=0

  for (int t = 0; t < T_STEPS; ++t) {
    // ---- gather: 2-way unrolled, 2 LDS instrs per nnz ----
    float acc0 = 0.0f, acc1 = 0.0f;
    unsigned k = kbeg + (unsigned)l16;
    for (; k + 16 < kend; k += 32) {
      const float2 p0 = s_pk[k];
      const float2 p1 = s_pk[k + 16];
      acc0 += p0.x * s_h[__float_as_uint(p0.y)];
      acc1 += p1.x * s_h[__float_as_uint(p1.y)];
    }
    if (k < kend) { const float2 p = s_pk[k]; acc0 += p.x * s_h[__float_as_uint(p.y)]; }
    float acc = acc0 + acc1;
    acc += __shfl_xor(acc, 1);
    acc += __shfl_xor(acc, 2);
    acc += __shfl_xor(acc, 4);
    acc += __shfl_xor(acc, 8);

    // prefetch next step's drive (1 cacheline per WG) to hide L3 latency
    const float dv_next = (l16 == 0 && t + 1 < T_STEPS)
                              ? drive[(size_t)(t + 1) * NN + myrow] : 0.0f;

    const int p = t & 1;
    float hn = 0.0f;
    if (l16 == 0) {
      hn = LEAK * tanhf(acc + dv) + (1.0f - LEAK) * s_h[myrow];
      states[(size_t)t * NN + myrow] = hn;            // plain store, for out_kernel
    }
    dv = dv_next;
    if (t == T_STEPS - 1) break;

    // ---- publish: 16 write-through data stores + release tag ----
    if (l16 == 0) {
      __hip_atomic_store(&rdata[(p * NWG + wg) * 16 + r], hn,
                         __ATOMIC_RELAXED, __HIP_MEMORY_SCOPE_AGENT);
    }
    __builtin_amdgcn_fence(__ATOMIC_RELEASE, "agent");  // data at coherence point
    __syncthreads();                                    // all 4 waves' data done
    if (tid == 0) {
      __hip_atomic_store(&tags[(p * NWG + wg) * TAG_STRIDE], (unsigned)(t + 1),
                         __ATOMIC_RELEASE, __HIP_MEMORY_SCOPE_AGENT);
    }

    // ---- consume: one producer per thread ----
    if (tid < NWG) {
      const unsigned tgt = (unsigned)(t + 1);
      while (__hip_atomic_load(&tags[(p * NWG + tid) * TAG_STRIDE],
                               __ATOMIC_RELAXED, __HIP_MEMORY_SCOPE_AGENT) < tgt)
        __builtin_amdgcn_s_sleep(1);
    }
    __builtin_amdgcn_fence(__ATOMIC_ACQUIRE, "agent");  // invalidate stale caches
    if (tid < NWG) {
      const float4* src = (const float4*)&rdata[(p * NWG + tid) * 16];
      float4* dst = (float4*)&s_h[tid * 16];
      dst[0] = src[0]; dst[1] = src[1]; dst[2] = src[2]; dst[3] = src[3];
    }
    __syncthreads();
  }
}

// ---------------------------------------------------------------------------
__global__ void out_kernel(const float* __restrict__ X, const float* __restrict__ states,
                           const float* __restrict__ WoT, float* __restrict__ out) {
  const int o = threadIdx.x & 31;
  const int tl = threadIdx.x >> 5;
  const int t = blockIdx.x * 8 + tl;
  float acc = 0.0f;
  const float* xrow = X + (size_t)t * N_IN;
#pragma unroll
  for (int k = 0; k < N_IN; ++k) acc += xrow[k] * WoT[k * N_OUT + o];
  const float* srow = states + (size_t)t * NN;
  for (int j = 0; j < NN; ++j) acc += srow[j] * WoT[(N_IN + j) * N_OUT + o];
  out[(size_t)t * N_OUT + o] = acc;
}

// ---------------------------------------------------------------------------
extern "C" void kernel_launch(void* const* d_in, const int* in_sizes, int n_in,
                              void* d_out, int out_size, void* d_ws, size_t ws_size,
                              hipStream_t stream) {
  const float* X     = (const float*)d_in[0];
  const float* y     = (const float*)d_in[1];
  const float* W_in  = (const float*)d_in[2];
  const float* W_res = (const float*)d_in[3];
  const float* W_fb  = (const float*)d_in[4];
  const float* W_out = (const float*)d_in[5];
  const float* b     = (const float*)d_in[6];
  float* out = (float*)d_out;

  // workspace layout (float offsets):
  //   drive : [2048][4000]        at 0            (8,192,000)
  //   states: [2048][4000]        at 8,192,000    (8,192,000)
  //   WoT   : [4032][32]          at 16,384,000   (129,024)
  //   tags  : [2][250][16] u32    at 16,513,024   (8,000)
  //   rdata : [2][250][16] f32    at 16,521,024   (8,000)
  float* ws = (float*)d_ws;
  float* drive   = ws;
  float* states  = ws + 8192000;
  float* WoT     = ws + 16384000;
  unsigned* tags = (unsigned*)(ws + 16513024);
  float* rdata   = ws + 16521024;

  hipMemsetAsync(tags, 0, 2 * NWG * TAG_STRIDE * sizeof(unsigned), stream);
  drive_kernel<<<dim3(16, T_STEPS), TPB, 0, stream>>>(X, y, W_in, W_fb, b, drive);
  transpose_wout_kernel<<<(N_OUT * NEXT + TPB - 1) / TPB, TPB, 0, stream>>>(W_out, WoT);
  esn_scan_kernel<<<NWG, TPB, 0, stream>>>(W_res, drive, states, tags, rdata);
  out_kernel<<<T_STEPS / 8, TPB, 0, stream>>>(X, states, WoT, out);
}

// Round 4
// 43101.978 us; speedup vs baseline: 1.9851x; 1.0930x over previous
//
#include <hip/hip_runtime.h>
#include <hip/hip_bf16.h>

#define T_STEPS 2048
#define NN 4000
#define N_IN 32
#define N_OUT 32
#define NEXT 4032          // N_IN + NN
#define NWG 250            // workgroups in persistent scan kernel
#define ROWS_PER_WG 16     // 250*16 = 4000
#define TPB 256
#define MAX_NNZ 7680       // per-WG LDS nnz capacity (mean 6400, sigma 76)
#define LEAK 0.99f
#define TAG_STRIDE 16      // u32s = 64B per tag line (own cacheline per WG)

// ---------------------------------------------------------------------------
// drive[t][n] = b + sum_k X[t][k]*W_in[n][k] + sum_k y[t][k]*W_fb[n][k]
// ---------------------------------------------------------------------------
__global__ void drive_kernel(const float* __restrict__ X, const float* __restrict__ y,
                             const float* __restrict__ W_in, const float* __restrict__ W_fb,
                             const float* __restrict__ b, float* __restrict__ drive) {
  __shared__ float s_x[N_IN];
  __shared__ float s_y[N_OUT];
  const int t = blockIdx.y;
  const int tid = threadIdx.x;
  if (tid < N_IN) s_x[tid] = X[t * N_IN + tid];
  else if (tid < N_IN + N_OUT) s_y[tid - N_IN] = y[t * N_OUT + (tid - N_IN)];
  __syncthreads();
  const int n = blockIdx.x * TPB + tid;
  if (n < NN) {
    float acc = b[0];
    const float* wi = W_in + (size_t)n * N_IN;
    const float* wf = W_fb + (size_t)n * N_OUT;
#pragma unroll
    for (int k = 0; k < N_IN; ++k) acc += s_x[k] * wi[k];
#pragma unroll
    for (int k = 0; k < N_OUT; ++k) acc += s_y[k] * wf[k];
    drive[(size_t)t * NN + n] = acc;
  }
}

// ---------------------------------------------------------------------------
__global__ void transpose_wout_kernel(const float* __restrict__ W_out, float* __restrict__ WoT) {
  const int idx = blockIdx.x * TPB + threadIdx.x;
  if (idx < N_OUT * NEXT) {
    const int o = idx / NEXT;
    const int k = idx % NEXT;
    WoT[k * N_OUT + o] = W_out[idx];
  }
}

// ---------------------------------------------------------------------------
// Persistent scan kernel. 250 WGs x 256 threads.
// CSR slice of 16 rows packed {val,col} in LDS.
// Two-level epoch barrier per step:
//   producers: 16 data stores (write-through agent) + release tag (own line)
//   master   : wave 0 of WG 0 polls all 250 tags (64 lanes x 4, independent
//              loads), then release-stores a single epoch line
//   consumers: ONE thread polls epoch, then all threads acquire-fence and
//              pull the compact 16KB h-vector with coalesced float4 loads.
// rdata double-buffered by step parity (max producer skew = 1 step).
// ---------------------------------------------------------------------------
__global__ __launch_bounds__(TPB, 1) void esn_scan_kernel(
    const float* __restrict__ W_res,
    const float* __restrict__ drive,
    float* __restrict__ states,
    unsigned* __restrict__ tags,    // [NWG][TAG_STRIDE], monotone step counters
    unsigned* __restrict__ epoch,   // [16], single line, monotone
    float* __restrict__ rdata) {    // [2][NN] compact h, parity-buffered
  __shared__ float2 s_pk[MAX_NNZ];          // {val, col bits} : one b64 per nnz
  __shared__ float s_h[NN];
  __shared__ unsigned s_cnt[ROWS_PER_WG];
  __shared__ unsigned s_start[ROWS_PER_WG + 1];

  const int tid = threadIdx.x;
  const int wg = blockIdx.x;
  const int row0 = wg * ROWS_PER_WG;
  const int wave = tid >> 6;
  const int lane = tid & 63;

  // ---- pass 1: count nonzeros per row ----
  for (int rl = 0; rl < 4; ++rl) {
    const int r = wave * 4 + rl;
    const float* wrow = W_res + (size_t)(row0 + r) * NN;
    unsigned cnt = 0;
    for (int c0 = 0; c0 < NN; c0 += 64) {
      const int c = c0 + lane;
      const float w = (c < NN) ? wrow[c] : 0.0f;
      cnt += (unsigned)__popcll(__ballot(w != 0.0f));
    }
    if (lane == 0) s_cnt[r] = cnt;
  }
  __syncthreads();
  if (tid == 0) {
    unsigned acc = 0;
    for (int r = 0; r < ROWS_PER_WG; ++r) { s_start[r] = acc; acc += s_cnt[r]; }
    s_start[ROWS_PER_WG] = acc;
  }
  __syncthreads();

  // ---- pass 2: ordered fill, packed {val, col} ----
  for (int rl = 0; rl < 4; ++rl) {
    const int r = wave * 4 + rl;
    const float* wrow = W_res + (size_t)(row0 + r) * NN;
    unsigned off = s_start[r];
    for (int c0 = 0; c0 < NN; c0 += 64) {
      const int c = c0 + lane;
      const float w = (c < NN) ? wrow[c] : 0.0f;
      const unsigned long long m = __ballot(w != 0.0f);
      if (w != 0.0f) {
        const unsigned pos = off + (unsigned)__popcll(m & ((1ULL << lane) - 1ULL));
        if (pos < MAX_NNZ) s_pk[pos] = make_float2(w, __uint_as_float((unsigned)c));
      }
      off += (unsigned)__popcll(m);
    }
  }

  for (int i = tid; i < NN; i += TPB) s_h[i] = 0.0f;   // h_0 = 0
  __syncthreads();

  const int r = tid >> 4;       // row within slice (0..15)
  const int l16 = tid & 15;     // lane within row-group
  const int myrow = row0 + r;
  const unsigned kbeg = s_start[r];
  const unsigned kend = s_start[r + 1];

  float dv = (l16 == 0) ? drive[myrow] : 0.0f;   // drive for t=0

  for (int t = 0; t < T_STEPS; ++t) {
    // ---- gather: 2-way unrolled, 2 LDS instrs per nnz ----
    float acc0 = 0.0f, acc1 = 0.0f;
    unsigned k = kbeg + (unsigned)l16;
    for (; k + 16 < kend; k += 32) {
      const float2 p0 = s_pk[k];
      const float2 p1 = s_pk[k + 16];
      acc0 += p0.x * s_h[__float_as_uint(p0.y)];
      acc1 += p1.x * s_h[__float_as_uint(p1.y)];
    }
    if (k < kend) { const float2 p = s_pk[k]; acc0 += p.x * s_h[__float_as_uint(p.y)]; }
    float acc = acc0 + acc1;
    acc += __shfl_xor(acc, 1);
    acc += __shfl_xor(acc, 2);
    acc += __shfl_xor(acc, 4);
    acc += __shfl_xor(acc, 8);

    // prefetch next step's drive (1 cacheline per WG) to hide latency
    const float dv_next = (l16 == 0 && t + 1 < T_STEPS)
                              ? drive[(size_t)(t + 1) * NN + myrow] : 0.0f;

    const int p = t & 1;
    float hn = 0.0f;
    if (l16 == 0) {
      hn = LEAK * tanhf(acc + dv) + (1.0f - LEAK) * s_h[myrow];
      states[(size_t)t * NN + myrow] = hn;            // plain store, for out_kernel
    }
    dv = dv_next;
    if (t == T_STEPS - 1) break;

    const unsigned tgt = (unsigned)(t + 1);

    // ---- publish: 16 write-through data stores + release tag ----
    if (l16 == 0) {
      __hip_atomic_store(&rdata[p * NN + myrow], hn,
                         __ATOMIC_RELAXED, __HIP_MEMORY_SCOPE_AGENT);
    }
    __builtin_amdgcn_fence(__ATOMIC_RELEASE, "agent");  // data at coherence point
    __syncthreads();                                    // all 4 waves' data done
    if (tid == 0) {
      __hip_atomic_store(&tags[wg * TAG_STRIDE], tgt, __ATOMIC_RELEASE,
                         __HIP_MEMORY_SCOPE_AGENT);
    }

    // ---- barrier level 1+2 ----
    if (wg == 0) {
      // master: wave 0 polls all 250 tags (4 independent loads per lane)
      if (tid < 64) {
        const int i0 = tid, i1 = tid + 64, i2 = tid + 128, i3 = tid + 192;
        for (;;) {
          const unsigned a = __hip_atomic_load(&tags[i0 * TAG_STRIDE],
                                __ATOMIC_RELAXED, __HIP_MEMORY_SCOPE_AGENT);
          const unsigned bb = __hip_atomic_load(&tags[i1 * TAG_STRIDE],
                                __ATOMIC_RELAXED, __HIP_MEMORY_SCOPE_AGENT);
          const unsigned cc = __hip_atomic_load(&tags[i2 * TAG_STRIDE],
                                __ATOMIC_RELAXED, __HIP_MEMORY_SCOPE_AGENT);
          const unsigned dd = (i3 < NWG)
                                ? __hip_atomic_load(&tags[i3 * TAG_STRIDE],
                                    __ATOMIC_RELAXED, __HIP_MEMORY_SCOPE_AGENT)
                                : ~0u;
          const bool ok = (a >= tgt) & (bb >= tgt) & (cc >= tgt) & (dd >= tgt);
          if (__all(ok)) break;
          __builtin_amdgcn_s_sleep(1);
        }
        __builtin_amdgcn_fence(__ATOMIC_ACQ_REL, "agent");  // chain release
        if (tid == 0)
          __hip_atomic_store(epoch, tgt, __ATOMIC_RELEASE,
                             __HIP_MEMORY_SCOPE_AGENT);
      }
      __syncthreads();
    } else {
      // consumer: one thread polls the single epoch line
      if (tid == 0) {
        while (__hip_atomic_load(epoch, __ATOMIC_RELAXED,
                                 __HIP_MEMORY_SCOPE_AGENT) < tgt)
          __builtin_amdgcn_s_sleep(1);
      }
      __syncthreads();
    }
    __builtin_amdgcn_fence(__ATOMIC_ACQUIRE, "agent");  // invalidate stale caches

    // ---- pull h_{t+1}: compact 16KB, fully coalesced float4 ----
    {
      const float4* src4 = (const float4*)&rdata[p * NN];
      float4* dst4 = (float4*)s_h;
      for (int i = tid; i < NN / 4; i += TPB) dst4[i] = src4[i];
    }
    __syncthreads();
  }
}

// ---------------------------------------------------------------------------
__global__ void out_kernel(const float* __restrict__ X, const float* __restrict__ states,
                           const float* __restrict__ WoT, float* __restrict__ out) {
  const int o = threadIdx.x & 31;
  const int tl = threadIdx.x >> 5;
  const int t = blockIdx.x * 8 + tl;
  float acc = 0.0f;
  const float* xrow = X + (size_t)t * N_IN;
#pragma unroll
  for (int k = 0; k < N_IN; ++k) acc += xrow[k] * WoT[k * N_OUT + o];
  const float* srow = states + (size_t)t * NN;
  for (int j = 0; j < NN; ++j) acc += srow[j] * WoT[(N_IN + j) * N_OUT + o];
  out[(size_t)t * N_OUT + o] = acc;
}

// ---------------------------------------------------------------------------
extern "C" void kernel_launch(void* const* d_in, const int* in_sizes, int n_in,
                              void* d_out, int out_size, void* d_ws, size_t ws_size,
                              hipStream_t stream) {
  const float* X     = (const float*)d_in[0];
  const float* y     = (const float*)d_in[1];
  const float* W_in  = (const float*)d_in[2];
  const float* W_res = (const float*)d_in[3];
  const float* W_fb  = (const float*)d_in[4];
  const float* W_out = (const float*)d_in[5];
  const float* b     = (const float*)d_in[6];
  float* out = (float*)d_out;

  // workspace layout (float offsets):
  //   drive : [2048][4000]        at 0            (8,192,000)
  //   states: [2048][4000]        at 8,192,000    (8,192,000)
  //   WoT   : [4032][32]          at 16,384,000   (129,024)
  //   tags  : [250][16] u32       at 16,513,024   (4,000 -> pad 4,096)
  //   epoch : [16] u32            at 16,517,120   (16)
  //   rdata : [2][4000] f32       at 16,517,136   (8,000)
  float* ws = (float*)d_ws;
  float* drive    = ws;
  float* states   = ws + 8192000;
  float* WoT      = ws + 16384000;
  unsigned* tags  = (unsigned*)(ws + 16513024);
  unsigned* epoch = (unsigned*)(ws + 16517120);
  float* rdata    = ws + 16517136;

  hipMemsetAsync(tags, 0, (4096 + 16) * sizeof(unsigned), stream);  // tags+epoch
  drive_kernel<<<dim3(16, T_STEPS), TPB, 0, stream>>>(X, y, W_in, W_fb, b, drive);
  transpose_wout_kernel<<<(N_OUT * NEXT + TPB - 1) / TPB, TPB, 0, stream>>>(W_out, WoT);
  esn_scan_kernel<<<NWG, TPB, 0, stream>>>(W_res, drive, states, tags, epoch, rdata);
  out_kernel<<<T_STEPS / 8, TPB, 0, stream>>>(X, states, WoT, out);
}

// Round 6
// 42101.151 us; speedup vs baseline: 2.0323x; 1.0238x over previous
//
#include <hip/hip_runtime.h>
#include <hip/hip_bf16.h>

#define T_STEPS 2048
#define NN 4000
#define N_IN 32
#define N_OUT 32
#define NEXT 4032          // N_IN + NN
#define NWG 250            // workgroups in persistent scan kernel
#define ROWS_PER_WG 16     // 250*16 = 4000
#define TPB 256
#define MAX_NNZ 7680       // per-WG LDS nnz capacity (mean 6400, sigma 76)
#define LEAK 0.99f
#define TAG_STRIDE 16      // u32s = 64B per tag line (own cacheline per WG)

// ---------------------------------------------------------------------------
// drive[t][n] = b + sum_k X[t][k]*W_in[n][k] + sum_k y[t][k]*W_fb[n][k]
// ---------------------------------------------------------------------------
__global__ void drive_kernel(const float* __restrict__ X, const float* __restrict__ y,
                             const float* __restrict__ W_in, const float* __restrict__ W_fb,
                             const float* __restrict__ b, float* __restrict__ drive) {
  __shared__ float s_x[N_IN];
  __shared__ float s_y[N_OUT];
  const int t = blockIdx.y;
  const int tid = threadIdx.x;
  if (tid < N_IN) s_x[tid] = X[t * N_IN + tid];
  else if (tid < N_IN + N_OUT) s_y[tid - N_IN] = y[t * N_OUT + (tid - N_IN)];
  __syncthreads();
  const int n = blockIdx.x * TPB + tid;
  if (n < NN) {
    float acc = b[0];
    const float* wi = W_in + (size_t)n * N_IN;
    const float* wf = W_fb + (size_t)n * N_OUT;
#pragma unroll
    for (int k = 0; k < N_IN; ++k) acc += s_x[k] * wi[k];
#pragma unroll
    for (int k = 0; k < N_OUT; ++k) acc += s_y[k] * wf[k];
    drive[(size_t)t * NN + n] = acc;
  }
}

// ---------------------------------------------------------------------------
__global__ void transpose_wout_kernel(const float* __restrict__ W_out, float* __restrict__ WoT) {
  const int idx = blockIdx.x * TPB + threadIdx.x;
  if (idx < N_OUT * NEXT) {
    const int o = idx / NEXT;
    const int k = idx % NEXT;
    WoT[k * N_OUT + o] = W_out[idx];
  }
}

// ---------------------------------------------------------------------------
// Persistent scan kernel. 250 WGs x 256 threads, 1 WG/CU.
// CSR slice of 16 rows packed {val,col} in LDS.
// Two-level epoch barrier per step (R4 structure) with HOT spinning (DVFS
// test), divergence-safe:
//  - any wave containing a spin loop has NO second spin loop for its other
//    lanes (they wait masked at reconvergence — exit depends only on an
//    external event, never on a sibling lane of the same wave)
//  - burner loops live only in waves 1..3, released by LDS flag s_go.
// h published directly into states[t] via agent-scope write-through stores.
// ---------------------------------------------------------------------------
__global__ __launch_bounds__(TPB, 1) void esn_scan_kernel(
    const float* __restrict__ W_res,
    const float* __restrict__ drive,
    float* __restrict__ states,
    unsigned* __restrict__ tags,    // [NWG][TAG_STRIDE], monotone step counters
    unsigned* __restrict__ epoch) { // [16], single line, monotone
  __shared__ float2 s_pk[MAX_NNZ];          // {val, col bits} : one b64 per nnz
  __shared__ float s_h[NN];
  __shared__ unsigned s_cnt[ROWS_PER_WG];
  __shared__ unsigned s_start[ROWS_PER_WG + 1];
  __shared__ unsigned s_go;

  const int tid = threadIdx.x;
  const int wg = blockIdx.x;
  const int row0 = wg * ROWS_PER_WG;
  const int wave = tid >> 6;
  const int lane = tid & 63;

  // ---- pass 1: count nonzeros per row ----
  for (int rl = 0; rl < 4; ++rl) {
    const int r = wave * 4 + rl;
    const float* wrow = W_res + (size_t)(row0 + r) * NN;
    unsigned cnt = 0;
    for (int c0 = 0; c0 < NN; c0 += 64) {
      const int c = c0 + lane;
      const float w = (c < NN) ? wrow[c] : 0.0f;
      cnt += (unsigned)__popcll(__ballot(w != 0.0f));
    }
    if (lane == 0) s_cnt[r] = cnt;
  }
  __syncthreads();
  if (tid == 0) {
    unsigned acc = 0;
    for (int r = 0; r < ROWS_PER_WG; ++r) { s_start[r] = acc; acc += s_cnt[r]; }
    s_start[ROWS_PER_WG] = acc;
  }
  __syncthreads();

  // ---- pass 2: ordered fill, packed {val, col} ----
  for (int rl = 0; rl < 4; ++rl) {
    const int r = wave * 4 + rl;
    const float* wrow = W_res + (size_t)(row0 + r) * NN;
    unsigned off = s_start[r];
    for (int c0 = 0; c0 < NN; c0 += 64) {
      const int c = c0 + lane;
      const float w = (c < NN) ? wrow[c] : 0.0f;
      const unsigned long long m = __ballot(w != 0.0f);
      if (w != 0.0f) {
        const unsigned pos = off + (unsigned)__popcll(m & ((1ULL << lane) - 1ULL));
        if (pos < MAX_NNZ) s_pk[pos] = make_float2(w, __uint_as_float((unsigned)c));
      }
      off += (unsigned)__popcll(m);
    }
  }

  for (int i = tid; i < NN; i += TPB) s_h[i] = 0.0f;   // h_0 = 0
  __syncthreads();

  const int r = tid >> 4;       // row within slice (0..15)
  const int l16 = tid & 15;     // lane within row-group
  const int myrow = row0 + r;
  const unsigned kbeg = s_start[r];
  const unsigned kend = s_start[r + 1];

  float dv = (l16 == 0) ? drive[myrow] : 0.0f;   // drive for t=0
  float junk = (float)tid * 1e-7f + 1.0f;        // burn accumulator (kept live)

  for (int t = 0; t < T_STEPS; ++t) {
    // ---- gather: 2-way unrolled, 2 LDS instrs per nnz ----
    float acc0 = 0.0f, acc1 = 0.0f;
    unsigned k = kbeg + (unsigned)l16;
    for (; k + 16 < kend; k += 32) {
      const float2 p0 = s_pk[k];
      const float2 p1 = s_pk[k + 16];
      acc0 += p0.x * s_h[__float_as_uint(p0.y)];
      acc1 += p1.x * s_h[__float_as_uint(p1.y)];
    }
    if (k < kend) { const float2 p = s_pk[k]; acc0 += p.x * s_h[__float_as_uint(p.y)]; }
    float acc = acc0 + acc1;
    acc += __shfl_xor(acc, 1);
    acc += __shfl_xor(acc, 2);
    acc += __shfl_xor(acc, 4);
    acc += __shfl_xor(acc, 8);

    // prefetch next step's drive (1 cacheline per WG) to hide latency
    const float dv_next = (l16 == 0 && t + 1 < T_STEPS)
                              ? drive[(size_t)(t + 1) * NN + myrow] : 0.0f;

    if (l16 == 0) {
      const float hn = LEAK * tanhf(acc + dv) + (1.0f - LEAK) * s_h[myrow];
      // publish: write-through agent store, doubles as out_kernel's input
      __hip_atomic_store(&states[(size_t)t * NN + myrow], hn,
                         __ATOMIC_RELAXED, __HIP_MEMORY_SCOPE_AGENT);
    }
    dv = dv_next;
    if (t == T_STEPS - 1) break;

    const unsigned tgt = (unsigned)(t + 1);

    if (tid == 0) __hip_atomic_store(&s_go, 0u, __ATOMIC_RELAXED,
                                     __HIP_MEMORY_SCOPE_WORKGROUP);
    __builtin_amdgcn_fence(__ATOMIC_RELEASE, "agent");  // h at coherence point
    __syncthreads();                                    // all waves fenced + s_go=0 visible
    if (tid == 0) {
      __hip_atomic_store(&tags[wg * TAG_STRIDE], tgt, __ATOMIC_RELEASE,
                         __HIP_MEMORY_SCOPE_AGENT);
    }

    // ---- barrier: hot spins; burners only in waves 1..3 ----
    if (wg == 0) {
      if (tid < 64) {
        // master wave: hot quad-poll all 250 tag lines (wave-uniform exit)
        const int i0 = tid, i1 = tid + 64, i2 = tid + 128, i3 = tid + 192;
        for (;;) {
          const unsigned a = __hip_atomic_load(&tags[i0 * TAG_STRIDE],
                                __ATOMIC_RELAXED, __HIP_MEMORY_SCOPE_AGENT);
          const unsigned bb = __hip_atomic_load(&tags[i1 * TAG_STRIDE],
                                __ATOMIC_RELAXED, __HIP_MEMORY_SCOPE_AGENT);
          const unsigned cc = __hip_atomic_load(&tags[i2 * TAG_STRIDE],
                                __ATOMIC_RELAXED, __HIP_MEMORY_SCOPE_AGENT);
          const unsigned dd = (i3 < NWG)
                                ? __hip_atomic_load(&tags[i3 * TAG_STRIDE],
                                    __ATOMIC_RELAXED, __HIP_MEMORY_SCOPE_AGENT)
                                : ~0u;
          const bool ok = (a >= tgt) & (bb >= tgt) & (cc >= tgt) & (dd >= tgt);
          if (__all(ok)) break;
        }
        if (tid == 0) {
          __builtin_amdgcn_fence(__ATOMIC_ACQ_REL, "agent");
          __hip_atomic_store(epoch, tgt, __ATOMIC_RELEASE,
                             __HIP_MEMORY_SCOPE_AGENT);
          __hip_atomic_store(&s_go, 1u, __ATOMIC_RELEASE,
                             __HIP_MEMORY_SCOPE_WORKGROUP);
        }
        // lanes 1..63: no loop — wait masked at reconvergence
      } else {
        // waves 1..3: burn until lane 0 of wave 0 releases s_go
        while (!__hip_atomic_load(&s_go, __ATOMIC_ACQUIRE,
                                  __HIP_MEMORY_SCOPE_WORKGROUP)) {
#pragma unroll
          for (int z = 0; z < 32; ++z)
            junk = __builtin_fmaf(junk, 1.0000001f, 1.1754944e-38f);
        }
      }
    } else {
      if (tid == 0) {
        // ONLY spin loop in wave 0: poll epoch hot with FMA backoff
        for (;;) {
          if (__hip_atomic_load(epoch, __ATOMIC_RELAXED,
                                __HIP_MEMORY_SCOPE_AGENT) >= tgt) break;
#pragma unroll
          for (int z = 0; z < 64; ++z)
            junk = __builtin_fmaf(junk, 1.0000001f, 1.1754944e-38f);
        }
        __hip_atomic_store(&s_go, 1u, __ATOMIC_RELEASE,
                           __HIP_MEMORY_SCOPE_WORKGROUP);
      } else if (tid >= 64) {
        // waves 1..3: burn until released (cross-wave dependency only)
        while (!__hip_atomic_load(&s_go, __ATOMIC_ACQUIRE,
                                  __HIP_MEMORY_SCOPE_WORKGROUP)) {
#pragma unroll
          for (int z = 0; z < 32; ++z)
            junk = __builtin_fmaf(junk, 1.0000001f, 1.1754944e-38f);
        }
      }
      // tid 1..63: empty path, wait masked at reconvergence
    }
    asm volatile("" :: "v"(junk));   // keep burn chain live, no output effect
    __syncthreads();
    __builtin_amdgcn_fence(__ATOMIC_ACQUIRE, "agent");  // invalidate stale L1/L2

    // ---- pull h_{t+1} = states[t][:] : 16KB coalesced float4 ----
    {
      const float4* src4 = (const float4*)(states + (size_t)t * NN);
      float4* dst4 = (float4*)s_h;
      for (int i = tid; i < NN / 4; i += TPB) dst4[i] = src4[i];
    }
    __syncthreads();
  }
}

// ---------------------------------------------------------------------------
__global__ void out_kernel(const float* __restrict__ X, const float* __restrict__ states,
                           const float* __restrict__ WoT, float* __restrict__ out) {
  const int o = threadIdx.x & 31;
  const int tl = threadIdx.x >> 5;
  const int t = blockIdx.x * 8 + tl;
  float acc = 0.0f;
  const float* xrow = X + (size_t)t * N_IN;
#pragma unroll
  for (int k = 0; k < N_IN; ++k) acc += xrow[k] * WoT[k * N_OUT + o];
  const float* srow = states + (size_t)t * NN;
  for (int j = 0; j < NN; ++j) acc += srow[j] * WoT[(N_IN + j) * N_OUT + o];
  out[(size_t)t * N_OUT + o] = acc;
}

// ---------------------------------------------------------------------------
extern "C" void kernel_launch(void* const* d_in, const int* in_sizes, int n_in,
                              void* d_out, int out_size, void* d_ws, size_t ws_size,
                              hipStream_t stream) {
  const float* X     = (const float*)d_in[0];
  const float* y     = (const float*)d_in[1];
  const float* W_in  = (const float*)d_in[2];
  const float* W_res = (const float*)d_in[3];
  const float* W_fb  = (const float*)d_in[4];
  const float* W_out = (const float*)d_in[5];
  const float* b     = (const float*)d_in[6];
  float* out = (float*)d_out;

  // workspace layout (float offsets):
  //   drive : [2048][4000]        at 0            (8,192,000)
  //   states: [2048][4000]        at 8,192,000    (8,192,000)
  //   WoT   : [4032][32]          at 16,384,000   (129,024)
  //   tags  : [250][16] u32       at 16,513,024   (4,000 -> pad 4,096)
  //   epoch : [16] u32            at 16,517,120   (16)
  float* ws = (float*)d_ws;
  float* drive    = ws;
  float* states   = ws + 8192000;
  float* WoT      = ws + 16384000;
  unsigned* tags  = (unsigned*)(ws + 16513024);
  unsigned* epoch = (unsigned*)(ws + 16517120);

  hipMemsetAsync(tags, 0, (4096 + 16) * sizeof(unsigned), stream);  // tags+epoch
  drive_kernel<<<dim3(16, T_STEPS), TPB, 0, stream>>>(X, y, W_in, W_fb, b, drive);
  transpose_wout_kernel<<<(N_OUT * NEXT + TPB - 1) / TPB, TPB, 0, stream>>>(W_out, WoT);
  esn_scan_kernel<<<NWG, TPB, 0, stream>>>(W_res, drive, states, tags, epoch);
  out_kernel<<<T_STEPS / 8, TPB, 0, stream>>>(X, states, WoT, out);
}

// Round 7
// 40615.552 us; speedup vs baseline: 2.1066x; 1.0366x over previous
//
#include <hip/hip_runtime.h>
#include <hip/hip_bf16.h>

#define T_STEPS 2048
#define NN 4000
#define N_IN 32
#define N_OUT 32
#define NEXT 4032          // N_IN + NN
#define NWG 250            // workgroups in persistent scan kernel
#define ROWS_PER_WG 16     // 250*16 = 4000
#define TPB 256
#define MAX_NNZ 7680       // per-WG LDS nnz capacity (mean 6400, sigma 76)
#define LEAK 0.99f
#define TAG_STRIDE 16      // u32s = 64B per line (own cacheline per WG)

// ---------------------------------------------------------------------------
// drive[t][n] = b + sum_k X[t][k]*W_in[n][k] + sum_k y[t][k]*W_fb[n][k]
// ---------------------------------------------------------------------------
__global__ void drive_kernel(const float* __restrict__ X, const float* __restrict__ y,
                             const float* __restrict__ W_in, const float* __restrict__ W_fb,
                             const float* __restrict__ b, float* __restrict__ drive) {
  __shared__ float s_x[N_IN];
  __shared__ float s_y[N_OUT];
  const int t = blockIdx.y;
  const int tid = threadIdx.x;
  if (tid < N_IN) s_x[tid] = X[t * N_IN + tid];
  else if (tid < N_IN + N_OUT) s_y[tid - N_IN] = y[t * N_OUT + (tid - N_IN)];
  __syncthreads();
  const int n = blockIdx.x * TPB + tid;
  if (n < NN) {
    float acc = b[0];
    const float* wi = W_in + (size_t)n * N_IN;
    const float* wf = W_fb + (size_t)n * N_OUT;
#pragma unroll
    for (int k = 0; k < N_IN; ++k) acc += s_x[k] * wi[k];
#pragma unroll
    for (int k = 0; k < N_OUT; ++k) acc += s_y[k] * wf[k];
    drive[(size_t)t * NN + n] = acc;
  }
}

// ---------------------------------------------------------------------------
__global__ void transpose_wout_kernel(const float* __restrict__ W_out, float* __restrict__ WoT) {
  const int idx = blockIdx.x * TPB + threadIdx.x;
  if (idx < N_OUT * NEXT) {
    const int o = idx / NEXT;
    const int k = idx % NEXT;
    WoT[k * N_OUT + o] = W_out[idx];
  }
}

// ---------------------------------------------------------------------------
// Persistent scan kernel. 250 WGs x 256 threads, 1 WG/CU.
// CSR slice of 16 rows packed {val,col} in LDS.
// Per-step barrier with ZERO shared-reader cachelines (contention theory):
//   producers: h stores (agent WT) + release fence + tag[wg] (1 writer, read
//              by exactly one master lane)
//   master   : WG0 wave0 polls 250 tag lines (1 lane per line), then each
//              lane DIRECTLY stores the step into its 4 dedicated mailboxes
//   consumers: WG w polls ONLY mbox[w] (1 writer = master lane, 1 reader).
// ---------------------------------------------------------------------------
__global__ __launch_bounds__(TPB, 1) void esn_scan_kernel(
    const float* __restrict__ W_res,
    const float* __restrict__ drive,
    float* __restrict__ states,
    unsigned* __restrict__ tags,    // [NWG][TAG_STRIDE], monotone step counters
    unsigned* __restrict__ mbox) {  // [NWG][TAG_STRIDE], per-WG dedicated mailbox
  __shared__ float2 s_pk[MAX_NNZ];          // {val, col bits} : one b64 per nnz
  __shared__ float s_h[NN];
  __shared__ unsigned s_cnt[ROWS_PER_WG];
  __shared__ unsigned s_start[ROWS_PER_WG + 1];

  const int tid = threadIdx.x;
  const int wg = blockIdx.x;
  const int row0 = wg * ROWS_PER_WG;
  const int wave = tid >> 6;
  const int lane = tid & 63;

  // ---- pass 1: count nonzeros per row ----
  for (int rl = 0; rl < 4; ++rl) {
    const int r = wave * 4 + rl;
    const float* wrow = W_res + (size_t)(row0 + r) * NN;
    unsigned cnt = 0;
    for (int c0 = 0; c0 < NN; c0 += 64) {
      const int c = c0 + lane;
      const float w = (c < NN) ? wrow[c] : 0.0f;
      cnt += (unsigned)__popcll(__ballot(w != 0.0f));
    }
    if (lane == 0) s_cnt[r] = cnt;
  }
  __syncthreads();
  if (tid == 0) {
    unsigned acc = 0;
    for (int r = 0; r < ROWS_PER_WG; ++r) { s_start[r] = acc; acc += s_cnt[r]; }
    s_start[ROWS_PER_WG] = acc;
  }
  __syncthreads();

  // ---- pass 2: ordered fill, packed {val, col} ----
  for (int rl = 0; rl < 4; ++rl) {
    const int r = wave * 4 + rl;
    const float* wrow = W_res + (size_t)(row0 + r) * NN;
    unsigned off = s_start[r];
    for (int c0 = 0; c0 < NN; c0 += 64) {
      const int c = c0 + lane;
      const float w = (c < NN) ? wrow[c] : 0.0f;
      const unsigned long long m = __ballot(w != 0.0f);
      if (w != 0.0f) {
        const unsigned pos = off + (unsigned)__popcll(m & ((1ULL << lane) - 1ULL));
        if (pos < MAX_NNZ) s_pk[pos] = make_float2(w, __uint_as_float((unsigned)c));
      }
      off += (unsigned)__popcll(m);
    }
  }

  for (int i = tid; i < NN; i += TPB) s_h[i] = 0.0f;   // h_0 = 0
  __syncthreads();

  const int r = tid >> 4;       // row within slice (0..15)
  const int l16 = tid & 15;     // lane within row-group
  const int myrow = row0 + r;
  const unsigned kbeg = s_start[r];
  const unsigned kend = s_start[r + 1];

  float dv = (l16 == 0) ? drive[myrow] : 0.0f;   // drive for t=0

  for (int t = 0; t < T_STEPS; ++t) {
    // ---- gather: 2-way unrolled, 2 LDS instrs per nnz ----
    float acc0 = 0.0f, acc1 = 0.0f;
    unsigned k = kbeg + (unsigned)l16;
    for (; k + 16 < kend; k += 32) {
      const float2 p0 = s_pk[k];
      const float2 p1 = s_pk[k + 16];
      acc0 += p0.x * s_h[__float_as_uint(p0.y)];
      acc1 += p1.x * s_h[__float_as_uint(p1.y)];
    }
    if (k < kend) { const float2 p = s_pk[k]; acc0 += p.x * s_h[__float_as_uint(p.y)]; }
    float acc = acc0 + acc1;
    acc += __shfl_xor(acc, 1);
    acc += __shfl_xor(acc, 2);
    acc += __shfl_xor(acc, 4);
    acc += __shfl_xor(acc, 8);

    // prefetch next step's drive (1 cacheline per WG) to hide latency
    const float dv_next = (l16 == 0 && t + 1 < T_STEPS)
                              ? drive[(size_t)(t + 1) * NN + myrow] : 0.0f;

    if (l16 == 0) {
      const float hn = LEAK * tanhf(acc + dv) + (1.0f - LEAK) * s_h[myrow];
      // publish: write-through agent store, doubles as out_kernel's input
      __hip_atomic_store(&states[(size_t)t * NN + myrow], hn,
                         __ATOMIC_RELAXED, __HIP_MEMORY_SCOPE_AGENT);
    }
    dv = dv_next;
    if (t == T_STEPS - 1) break;

    const unsigned tgt = (unsigned)(t + 1);

    __builtin_amdgcn_fence(__ATOMIC_RELEASE, "agent");  // h at coherence point
    __syncthreads();                                    // all waves fenced
    if (tid == 0) {
      __hip_atomic_store(&tags[wg * TAG_STRIDE], tgt, __ATOMIC_RELEASE,
                         __HIP_MEMORY_SCOPE_AGENT);
    }

    // ---- barrier: no cacheline has more than one concurrent reader ----
    if (wg == 0) {
      if (tid < 64) {
        // master wave: poll 250 tag lines, one lane per line (4 each)
        const int i0 = tid, i1 = tid + 64, i2 = tid + 128, i3 = tid + 192;
        for (;;) {
          const unsigned a = __hip_atomic_load(&tags[i0 * TAG_STRIDE],
                                __ATOMIC_RELAXED, __HIP_MEMORY_SCOPE_AGENT);
          const unsigned bb = __hip_atomic_load(&tags[i1 * TAG_STRIDE],
                                __ATOMIC_RELAXED, __HIP_MEMORY_SCOPE_AGENT);
          const unsigned cc = __hip_atomic_load(&tags[i2 * TAG_STRIDE],
                                __ATOMIC_RELAXED, __HIP_MEMORY_SCOPE_AGENT);
          const unsigned dd = (i3 < NWG)
                                ? __hip_atomic_load(&tags[i3 * TAG_STRIDE],
                                    __ATOMIC_RELAXED, __HIP_MEMORY_SCOPE_AGENT)
                                : ~0u;
          const bool ok = (a >= tgt) & (bb >= tgt) & (cc >= tgt) & (dd >= tgt);
          if (__all(ok)) break;
          __builtin_amdgcn_s_sleep(1);
        }
        __builtin_amdgcn_fence(__ATOMIC_ACQ_REL, "agent");  // chain release
        // direct broadcast: each lane releases its 4 dedicated mailboxes
        __hip_atomic_store(&mbox[i0 * TAG_STRIDE], tgt, __ATOMIC_RELAXED,
                           __HIP_MEMORY_SCOPE_AGENT);   // mbox[0] unused, harmless
        __hip_atomic_store(&mbox[i1 * TAG_STRIDE], tgt, __ATOMIC_RELAXED,
                           __HIP_MEMORY_SCOPE_AGENT);
        __hip_atomic_store(&mbox[i2 * TAG_STRIDE], tgt, __ATOMIC_RELAXED,
                           __HIP_MEMORY_SCOPE_AGENT);
        if (i3 < NWG)
          __hip_atomic_store(&mbox[i3 * TAG_STRIDE], tgt, __ATOMIC_RELAXED,
                             __HIP_MEMORY_SCOPE_AGENT);
      }
      __syncthreads();
    } else {
      // consumer: ONE thread polls its OWN dedicated mailbox line
      if (tid == 0) {
        while (__hip_atomic_load(&mbox[wg * TAG_STRIDE], __ATOMIC_RELAXED,
                                 __HIP_MEMORY_SCOPE_AGENT) < tgt)
          __builtin_amdgcn_s_sleep(1);
      }
      __syncthreads();
    }
    __builtin_amdgcn_fence(__ATOMIC_ACQUIRE, "agent");  // invalidate stale L1/L2

    // ---- pull h_{t+1} = states[t][:] : 16KB coalesced float4 ----
    {
      const float4* src4 = (const float4*)(states + (size_t)t * NN);
      float4* dst4 = (float4*)s_h;
      for (int i = tid; i < NN / 4; i += TPB) dst4[i] = src4[i];
    }
    __syncthreads();
  }
}

// ---------------------------------------------------------------------------
__global__ void out_kernel(const float* __restrict__ X, const float* __restrict__ states,
                           const float* __restrict__ WoT, float* __restrict__ out) {
  const int o = threadIdx.x & 31;
  const int tl = threadIdx.x >> 5;
  const int t = blockIdx.x * 8 + tl;
  float acc = 0.0f;
  const float* xrow = X + (size_t)t * N_IN;
#pragma unroll
  for (int k = 0; k < N_IN; ++k) acc += xrow[k] * WoT[k * N_OUT + o];
  const float* srow = states + (size_t)t * NN;
  for (int j = 0; j < NN; ++j) acc += srow[j] * WoT[(N_IN + j) * N_OUT + o];
  out[(size_t)t * N_OUT + o] = acc;
}

// ---------------------------------------------------------------------------
extern "C" void kernel_launch(void* const* d_in, const int* in_sizes, int n_in,
                              void* d_out, int out_size, void* d_ws, size_t ws_size,
                              hipStream_t stream) {
  const float* X     = (const float*)d_in[0];
  const float* y     = (const float*)d_in[1];
  const float* W_in  = (const float*)d_in[2];
  const float* W_res = (const float*)d_in[3];
  const float* W_fb  = (const float*)d_in[4];
  const float* W_out = (const float*)d_in[5];
  const float* b     = (const float*)d_in[6];
  float* out = (float*)d_out;

  // workspace layout (float offsets):
  //   drive : [2048][4000]        at 0            (8,192,000)
  //   states: [2048][4000]        at 8,192,000    (8,192,000)
  //   WoT   : [4032][32]          at 16,384,000   (129,024)
  //   tags  : [250][16] u32       at 16,513,024   (4,000 -> pad 4,096)
  //   mbox  : [250][16] u32       at 16,517,120   (4,000 -> pad 4,096)
  float* ws = (float*)d_ws;
  float* drive    = ws;
  float* states   = ws + 8192000;
  float* WoT      = ws + 16384000;
  unsigned* tags  = (unsigned*)(ws + 16513024);
  unsigned* mbox  = (unsigned*)(ws + 16517120);

  hipMemsetAsync(tags, 0, 2 * 4096 * sizeof(unsigned), stream);  // tags+mbox
  drive_kernel<<<dim3(16, T_STEPS), TPB, 0, stream>>>(X, y, W_in, W_fb, b, drive);
  transpose_wout_kernel<<<(N_OUT * NEXT + TPB - 1) / TPB, TPB, 0, stream>>>(W_out, WoT);
  esn_scan_kernel<<<NWG, TPB, 0, stream>>>(W_res, drive, states, tags, mbox);
  out_kernel<<<T_STEPS / 8, TPB, 0, stream>>>(X, states, WoT, out);
}

// Round 8
// 11791.866 us; speedup vs baseline: 7.2561x; 3.4444x over previous
//
#include <hip/hip_runtime.h>
#include <hip/hip_bf16.h>

#define T_STEPS 2048
#define NN 4000
#define N_IN 32
#define N_OUT 32
#define NEXT 4032          // N_IN + NN
#define NWG 250            // workgroups in persistent scan kernel
#define ROWS_PER_WG 16     // 250*16 = 4000
#define TPB 256
#define MAX_NNZ 7680       // per-WG LDS nnz capacity (mean 6400, sigma 76)
#define LEAK 0.99f
#define TAG_STRIDE 16      // u32s = 64B per line (own cacheline per WG)

// ---------------------------------------------------------------------------
// drive[t][n] = b + sum_k X[t][k]*W_in[n][k] + sum_k y[t][k]*W_fb[n][k]
// ---------------------------------------------------------------------------
__global__ void drive_kernel(const float* __restrict__ X, const float* __restrict__ y,
                             const float* __restrict__ W_in, const float* __restrict__ W_fb,
                             const float* __restrict__ b, float* __restrict__ drive) {
  __shared__ float s_x[N_IN];
  __shared__ float s_y[N_OUT];
  const int t = blockIdx.y;
  const int tid = threadIdx.x;
  if (tid < N_IN) s_x[tid] = X[t * N_IN + tid];
  else if (tid < N_IN + N_OUT) s_y[tid - N_IN] = y[t * N_OUT + (tid - N_IN)];
  __syncthreads();
  const int n = blockIdx.x * TPB + tid;
  if (n < NN) {
    float acc = b[0];
    const float* wi = W_in + (size_t)n * N_IN;
    const float* wf = W_fb + (size_t)n * N_OUT;
#pragma unroll
    for (int k = 0; k < N_IN; ++k) acc += s_x[k] * wi[k];
#pragma unroll
    for (int k = 0; k < N_OUT; ++k) acc += s_y[k] * wf[k];
    drive[(size_t)t * NN + n] = acc;
  }
}

// ---------------------------------------------------------------------------
__global__ void transpose_wout_kernel(const float* __restrict__ W_out, float* __restrict__ WoT) {
  const int idx = blockIdx.x * TPB + threadIdx.x;
  if (idx < N_OUT * NEXT) {
    const int o = idx / NEXT;
    const int k = idx % NEXT;
    WoT[k * N_OUT + o] = W_out[idx];
  }
}

// ---------------------------------------------------------------------------
// Persistent scan kernel. 250 WGs x 256 threads, 1 WG/CU.
// CSR slice of 16 rows packed {val,col} in LDS.
// R7 topology, but ZERO per-step cache-maintenance (no buffer_wbl2/buffer_inv):
// all cross-WG traffic is relaxed agent-scope atomics (sc0 sc1: write-through
// stores, L2-bypassing loads). Ordering h-before-tag: s_waitcnt vmcnt(0)
// (WT stores are at the coherence point once drained — nothing dirty in L2).
// ---------------------------------------------------------------------------
__global__ __launch_bounds__(TPB, 1) void esn_scan_kernel(
    const float* __restrict__ W_res,
    const float* __restrict__ drive,
    float* __restrict__ states,
    unsigned* __restrict__ tags,    // [NWG][TAG_STRIDE], monotone step counters
    unsigned* __restrict__ mbox) {  // [NWG][TAG_STRIDE], per-WG dedicated mailbox
  __shared__ float2 s_pk[MAX_NNZ];          // {val, col bits} : one b64 per nnz
  __shared__ __align__(16) float s_h[NN];
  __shared__ unsigned s_cnt[ROWS_PER_WG];
  __shared__ unsigned s_start[ROWS_PER_WG + 1];

  const int tid = threadIdx.x;
  const int wg = blockIdx.x;
  const int row0 = wg * ROWS_PER_WG;
  const int wave = tid >> 6;
  const int lane = tid & 63;

  // ---- pass 1: count nonzeros per row ----
  for (int rl = 0; rl < 4; ++rl) {
    const int r = wave * 4 + rl;
    const float* wrow = W_res + (size_t)(row0 + r) * NN;
    unsigned cnt = 0;
    for (int c0 = 0; c0 < NN; c0 += 64) {
      const int c = c0 + lane;
      const float w = (c < NN) ? wrow[c] : 0.0f;
      cnt += (unsigned)__popcll(__ballot(w != 0.0f));
    }
    if (lane == 0) s_cnt[r] = cnt;
  }
  __syncthreads();
  if (tid == 0) {
    unsigned acc = 0;
    for (int r = 0; r < ROWS_PER_WG; ++r) { s_start[r] = acc; acc += s_cnt[r]; }
    s_start[ROWS_PER_WG] = acc;
  }
  __syncthreads();

  // ---- pass 2: ordered fill, packed {val, col} ----
  for (int rl = 0; rl < 4; ++rl) {
    const int r = wave * 4 + rl;
    const float* wrow = W_res + (size_t)(row0 + r) * NN;
    unsigned off = s_start[r];
    for (int c0 = 0; c0 < NN; c0 += 64) {
      const int c = c0 + lane;
      const float w = (c < NN) ? wrow[c] : 0.0f;
      const unsigned long long m = __ballot(w != 0.0f);
      if (w != 0.0f) {
        const unsigned pos = off + (unsigned)__popcll(m & ((1ULL << lane) - 1ULL));
        if (pos < MAX_NNZ) s_pk[pos] = make_float2(w, __uint_as_float((unsigned)c));
      }
      off += (unsigned)__popcll(m);
    }
  }

  for (int i = tid; i < NN; i += TPB) s_h[i] = 0.0f;   // h_0 = 0
  __syncthreads();

  const int r = tid >> 4;       // row within slice (0..15)
  const int l16 = tid & 15;     // lane within row-group
  const int myrow = row0 + r;
  const unsigned kbeg = s_start[r];
  const unsigned kend = s_start[r + 1];

  float dv = (l16 == 0) ? drive[myrow] : 0.0f;   // drive for t=0

  for (int t = 0; t < T_STEPS; ++t) {
    // ---- gather: 2-way unrolled, 2 LDS instrs per nnz ----
    float acc0 = 0.0f, acc1 = 0.0f;
    unsigned k = kbeg + (unsigned)l16;
    for (; k + 16 < kend; k += 32) {
      const float2 p0 = s_pk[k];
      const float2 p1 = s_pk[k + 16];
      acc0 += p0.x * s_h[__float_as_uint(p0.y)];
      acc1 += p1.x * s_h[__float_as_uint(p1.y)];
    }
    if (k < kend) { const float2 p = s_pk[k]; acc0 += p.x * s_h[__float_as_uint(p.y)]; }
    float acc = acc0 + acc1;
    acc += __shfl_xor(acc, 1);
    acc += __shfl_xor(acc, 2);
    acc += __shfl_xor(acc, 4);
    acc += __shfl_xor(acc, 8);

    // prefetch next step's drive (1 cacheline per WG) to hide latency
    const float dv_next = (l16 == 0 && t + 1 < T_STEPS)
                              ? drive[(size_t)(t + 1) * NN + myrow] : 0.0f;

    if (l16 == 0) {
      const float hn = LEAK * tanhf(acc + dv) + (1.0f - LEAK) * s_h[myrow];
      // publish: write-through agent store (sc0 sc1), also out_kernel's input
      __hip_atomic_store(&states[(size_t)t * NN + myrow], hn,
                         __ATOMIC_RELAXED, __HIP_MEMORY_SCOPE_AGENT);
    }
    dv = dv_next;
    if (t == T_STEPS - 1) break;

    const unsigned tgt = (unsigned)(t + 1);

    // ordering: WT h-stores drained to coherence point; NO buffer_wbl2
    asm volatile("s_waitcnt vmcnt(0)" ::: "memory");
    __syncthreads();                                    // all 4 waves drained
    if (tid == 0) {
      __hip_atomic_store(&tags[wg * TAG_STRIDE], tgt, __ATOMIC_RELAXED,
                         __HIP_MEMORY_SCOPE_AGENT);
    }

    // ---- barrier: single-reader lines only, no fences ----
    if (wg == 0) {
      if (tid < 64) {
        // master wave: poll 250 tag lines, one lane per line (4 each)
        const int i0 = tid, i1 = tid + 64, i2 = tid + 128, i3 = tid + 192;
        for (;;) {
          const unsigned a = __hip_atomic_load(&tags[i0 * TAG_STRIDE],
                                __ATOMIC_RELAXED, __HIP_MEMORY_SCOPE_AGENT);
          const unsigned bb = __hip_atomic_load(&tags[i1 * TAG_STRIDE],
                                __ATOMIC_RELAXED, __HIP_MEMORY_SCOPE_AGENT);
          const unsigned cc = __hip_atomic_load(&tags[i2 * TAG_STRIDE],
                                __ATOMIC_RELAXED, __HIP_MEMORY_SCOPE_AGENT);
          const unsigned dd = (i3 < NWG)
                                ? __hip_atomic_load(&tags[i3 * TAG_STRIDE],
                                    __ATOMIC_RELAXED, __HIP_MEMORY_SCOPE_AGENT)
                                : ~0u;
          const bool ok = (a >= tgt) & (bb >= tgt) & (cc >= tgt) & (dd >= tgt);
          if (__all(ok)) break;
          __builtin_amdgcn_s_sleep(1);
        }
        // direct broadcast: each lane releases its 4 dedicated mailboxes
        __hip_atomic_store(&mbox[i0 * TAG_STRIDE], tgt, __ATOMIC_RELAXED,
                           __HIP_MEMORY_SCOPE_AGENT);   // mbox[0] unused, harmless
        __hip_atomic_store(&mbox[i1 * TAG_STRIDE], tgt, __ATOMIC_RELAXED,
                           __HIP_MEMORY_SCOPE_AGENT);
        __hip_atomic_store(&mbox[i2 * TAG_STRIDE], tgt, __ATOMIC_RELAXED,
                           __HIP_MEMORY_SCOPE_AGENT);
        if (i3 < NWG)
          __hip_atomic_store(&mbox[i3 * TAG_STRIDE], tgt, __ATOMIC_RELAXED,
                             __HIP_MEMORY_SCOPE_AGENT);
      }
      __syncthreads();
    } else {
      // consumer: ONE thread polls its OWN dedicated mailbox line
      if (tid == 0) {
        while (__hip_atomic_load(&mbox[wg * TAG_STRIDE], __ATOMIC_RELAXED,
                                 __HIP_MEMORY_SCOPE_AGENT) < tgt)
          __builtin_amdgcn_s_sleep(1);
      }
      __syncthreads();
    }

    // ---- pull h_{t+1}: IF-direct 64-bit atomic loads (no buffer_inv) ----
    {
      const unsigned long long* src =
          (const unsigned long long*)(states + (size_t)t * NN);
      unsigned long long* dst = (unsigned long long*)s_h;
      for (int i = tid; i < NN / 2; i += TPB)
        dst[i] = __hip_atomic_load(&src[i], __ATOMIC_RELAXED,
                                   __HIP_MEMORY_SCOPE_AGENT);
    }
    __syncthreads();
  }
}

// ---------------------------------------------------------------------------
__global__ void out_kernel(const float* __restrict__ X, const float* __restrict__ states,
                           const float* __restrict__ WoT, float* __restrict__ out) {
  const int o = threadIdx.x & 31;
  const int tl = threadIdx.x >> 5;
  const int t = blockIdx.x * 8 + tl;
  float acc = 0.0f;
  const float* xrow = X + (size_t)t * N_IN;
#pragma unroll
  for (int k = 0; k < N_IN; ++k) acc += xrow[k] * WoT[k * N_OUT + o];
  const float* srow = states + (size_t)t * NN;
  for (int j = 0; j < NN; ++j) acc += srow[j] * WoT[(N_IN + j) * N_OUT + o];
  out[(size_t)t * N_OUT + o] = acc;
}

// ---------------------------------------------------------------------------
extern "C" void kernel_launch(void* const* d_in, const int* in_sizes, int n_in,
                              void* d_out, int out_size, void* d_ws, size_t ws_size,
                              hipStream_t stream) {
  const float* X     = (const float*)d_in[0];
  const float* y     = (const float*)d_in[1];
  const float* W_in  = (const float*)d_in[2];
  const float* W_res = (const float*)d_in[3];
  const float* W_fb  = (const float*)d_in[4];
  const float* W_out = (const float*)d_in[5];
  const float* b     = (const float*)d_in[6];
  float* out = (float*)d_out;

  // workspace layout (float offsets):
  //   drive : [2048][4000]        at 0            (8,192,000)
  //   states: [2048][4000]        at 8,192,000    (8,192,000)
  //   WoT   : [4032][32]          at 16,384,000   (129,024)
  //   tags  : [250][16] u32       at 16,513,024   (4,000 -> pad 4,096)
  //   mbox  : [250][16] u32       at 16,517,120   (4,000 -> pad 4,096)
  float* ws = (float*)d_ws;
  float* drive    = ws;
  float* states   = ws + 8192000;
  float* WoT      = ws + 16384000;
  unsigned* tags  = (unsigned*)(ws + 16513024);
  unsigned* mbox  = (unsigned*)(ws + 16517120);

  hipMemsetAsync(tags, 0, 2 * 4096 * sizeof(unsigned), stream);  // tags+mbox
  drive_kernel<<<dim3(16, T_STEPS), TPB, 0, stream>>>(X, y, W_in, W_fb, b, drive);
  transpose_wout_kernel<<<(N_OUT * NEXT + TPB - 1) / TPB, TPB, 0, stream>>>(W_out, WoT);
  esn_scan_kernel<<<NWG, TPB, 0, stream>>>(W_res, drive, states, tags, mbox);
  out_kernel<<<T_STEPS / 8, TPB, 0, stream>>>(X, states, WoT, out);
}

// Round 9
// 9995.900 us; speedup vs baseline: 8.5598x; 1.1797x over previous
//
#include <hip/hip_runtime.h>
#include <hip/hip_bf16.h>

#define T_STEPS 2048
#define NN 4000
#define N_IN 32
#define N_OUT 32
#define NEXT 4032          // N_IN + NN
#define NWG 250            // workgroups in persistent scan kernel
#define ROWS_PER_WG 16     // 250*16 = 4000
#define TPB 256
#define MAX_NNZ 7680       // per-WG LDS nnz capacity (mean 6400, sigma 76)
#define LEAK 0.99f
#define TAG_STRIDE 16      // u32s = 64B per line (own cacheline per WG)

// ---------------------------------------------------------------------------
// drive[t][n] = b + sum_k X[t][k]*W_in[n][k] + sum_k y[t][k]*W_fb[n][k]
// ---------------------------------------------------------------------------
__global__ void drive_kernel(const float* __restrict__ X, const float* __restrict__ y,
                             const float* __restrict__ W_in, const float* __restrict__ W_fb,
                             const float* __restrict__ b, float* __restrict__ drive) {
  __shared__ float s_x[N_IN];
  __shared__ float s_y[N_OUT];
  const int t = blockIdx.y;
  const int tid = threadIdx.x;
  if (tid < N_IN) s_x[tid] = X[t * N_IN + tid];
  else if (tid < N_IN + N_OUT) s_y[tid - N_IN] = y[t * N_OUT + (tid - N_IN)];
  __syncthreads();
  const int n = blockIdx.x * TPB + tid;
  if (n < NN) {
    float acc = b[0];
    const float* wi = W_in + (size_t)n * N_IN;
    const float* wf = W_fb + (size_t)n * N_OUT;
#pragma unroll
    for (int k = 0; k < N_IN; ++k) acc += s_x[k] * wi[k];
#pragma unroll
    for (int k = 0; k < N_OUT; ++k) acc += s_y[k] * wf[k];
    drive[(size_t)t * NN + n] = acc;
  }
}

// ---------------------------------------------------------------------------
__global__ void transpose_wout_kernel(const float* __restrict__ W_out, float* __restrict__ WoT) {
  const int idx = blockIdx.x * TPB + threadIdx.x;
  if (idx < N_OUT * NEXT) {
    const int o = idx / NEXT;
    const int k = idx % NEXT;
    WoT[k * N_OUT + o] = W_out[idx];
  }
}

// ---------------------------------------------------------------------------
// Persistent scan kernel. 250 WGs x 256 threads, 1 WG/CU.
// CSR slice of 16 rows packed {val,col} in LDS.
// ZERO per-step cache maintenance (R8, confirmed win) + FLAT fused barrier:
// no master/mbox hops — each consumer thread polls ONE producer's tag and on
// detection immediately pulls that producer's 64B h-chunk (IF-direct b64
// atomic loads) into LDS. Producer index staggered by wg to decorrelate
// same-line polling; LDS writes rotated by tid&7 to spread banks.
// ---------------------------------------------------------------------------
__global__ __launch_bounds__(TPB, 1) void esn_scan_kernel(
    const float* __restrict__ W_res,
    const float* __restrict__ drive,
    float* __restrict__ states,
    unsigned* __restrict__ tags) {  // [NWG][TAG_STRIDE], monotone step counters
  __shared__ float2 s_pk[MAX_NNZ];          // {val, col bits} : one b64 per nnz
  __shared__ __align__(16) float s_h[NN];
  __shared__ unsigned s_cnt[ROWS_PER_WG];
  __shared__ unsigned s_start[ROWS_PER_WG + 1];

  const int tid = threadIdx.x;
  const int wg = blockIdx.x;
  const int row0 = wg * ROWS_PER_WG;
  const int wave = tid >> 6;
  const int lane = tid & 63;

  // ---- pass 1: count nonzeros per row ----
  for (int rl = 0; rl < 4; ++rl) {
    const int r = wave * 4 + rl;
    const float* wrow = W_res + (size_t)(row0 + r) * NN;
    unsigned cnt = 0;
    for (int c0 = 0; c0 < NN; c0 += 64) {
      const int c = c0 + lane;
      const float w = (c < NN) ? wrow[c] : 0.0f;
      cnt += (unsigned)__popcll(__ballot(w != 0.0f));
    }
    if (lane == 0) s_cnt[r] = cnt;
  }
  __syncthreads();
  if (tid == 0) {
    unsigned acc = 0;
    for (int r = 0; r < ROWS_PER_WG; ++r) { s_start[r] = acc; acc += s_cnt[r]; }
    s_start[ROWS_PER_WG] = acc;
  }
  __syncthreads();

  // ---- pass 2: ordered fill, packed {val, col} ----
  for (int rl = 0; rl < 4; ++rl) {
    const int r = wave * 4 + rl;
    const float* wrow = W_res + (size_t)(row0 + r) * NN;
    unsigned off = s_start[r];
    for (int c0 = 0; c0 < NN; c0 += 64) {
      const int c = c0 + lane;
      const float w = (c < NN) ? wrow[c] : 0.0f;
      const unsigned long long m = __ballot(w != 0.0f);
      if (w != 0.0f) {
        const unsigned pos = off + (unsigned)__popcll(m & ((1ULL << lane) - 1ULL));
        if (pos < MAX_NNZ) s_pk[pos] = make_float2(w, __uint_as_float((unsigned)c));
      }
      off += (unsigned)__popcll(m);
    }
  }

  for (int i = tid; i < NN; i += TPB) s_h[i] = 0.0f;   // h_0 = 0
  __syncthreads();

  const int r = tid >> 4;       // row within slice (0..15)
  const int l16 = tid & 15;     // lane within row-group
  const int myrow = row0 + r;
  const unsigned kbeg = s_start[r];
  const unsigned kend = s_start[r + 1];

  // fused-barrier assignment: this thread polls+pulls producer `p`
  const int p = (tid < NWG) ? (tid + wg) % NWG : 0;
  const int jrot = tid & 7;     // rotation for LDS bank spread

  float dv = (l16 == 0) ? drive[myrow] : 0.0f;   // drive for t=0

  for (int t = 0; t < T_STEPS; ++t) {
    // ---- gather: 2-way unrolled, 2 LDS instrs per nnz ----
    float acc0 = 0.0f, acc1 = 0.0f;
    unsigned k = kbeg + (unsigned)l16;
    for (; k + 16 < kend; k += 32) {
      const float2 p0 = s_pk[k];
      const float2 p1 = s_pk[k + 16];
      acc0 += p0.x * s_h[__float_as_uint(p0.y)];
      acc1 += p1.x * s_h[__float_as_uint(p1.y)];
    }
    if (k < kend) { const float2 pk = s_pk[k]; acc0 += pk.x * s_h[__float_as_uint(pk.y)]; }
    float acc = acc0 + acc1;
    acc += __shfl_xor(acc, 1);
    acc += __shfl_xor(acc, 2);
    acc += __shfl_xor(acc, 4);
    acc += __shfl_xor(acc, 8);

    // prefetch next step's drive (1 cacheline per WG) to hide latency
    const float dv_next = (l16 == 0 && t + 1 < T_STEPS)
                              ? drive[(size_t)(t + 1) * NN + myrow] : 0.0f;

    if (l16 == 0) {
      const float hn = LEAK * tanhf(acc + dv) + (1.0f - LEAK) * s_h[myrow];
      // publish: write-through agent store (sc0 sc1), also out_kernel's input
      __hip_atomic_store(&states[(size_t)t * NN + myrow], hn,
                         __ATOMIC_RELAXED, __HIP_MEMORY_SCOPE_AGENT);
    }
    dv = dv_next;
    if (t == T_STEPS - 1) break;

    const unsigned tgt = (unsigned)(t + 1);

    // ordering: WT h-stores drained to coherence point (no buffer_wbl2)
    asm volatile("s_waitcnt vmcnt(0)" ::: "memory");
    __syncthreads();                                    // all 4 waves drained
    if (tid == 0) {
      __hip_atomic_store(&tags[wg * TAG_STRIDE], tgt, __ATOMIC_RELAXED,
                         __HIP_MEMORY_SCOPE_AGENT);
    }

    // ---- fused detect+pull: thread tid handles producer p ----
    if (tid < NWG) {
      while (__hip_atomic_load(&tags[p * TAG_STRIDE], __ATOMIC_RELAXED,
                               __HIP_MEMORY_SCOPE_AGENT) < tgt)
        __builtin_amdgcn_s_sleep(1);
      // pull p's 16 h values (64B) via IF-direct b64 atomic loads,
      // rotated start to spread LDS write banks (~4-way instead of 16-way)
      const unsigned long long* src =
          (const unsigned long long*)(states + (size_t)t * NN + p * 16);
      unsigned long long* dst = (unsigned long long*)&s_h[p * 16];
#pragma unroll
      for (int jj = 0; jj < 8; ++jj) {
        const int j = (jrot + jj) & 7;
        dst[j] = __hip_atomic_load(&src[j], __ATOMIC_RELAXED,
                                   __HIP_MEMORY_SCOPE_AGENT);
      }
    }
    __syncthreads();
  }
}

// ---------------------------------------------------------------------------
__global__ void out_kernel(const float* __restrict__ X, const float* __restrict__ states,
                           const float* __restrict__ WoT, float* __restrict__ out) {
  const int o = threadIdx.x & 31;
  const int tl = threadIdx.x >> 5;
  const int t = blockIdx.x * 8 + tl;
  float acc = 0.0f;
  const float* xrow = X + (size_t)t * N_IN;
#pragma unroll
  for (int k = 0; k < N_IN; ++k) acc += xrow[k] * WoT[k * N_OUT + o];
  const float* srow = states + (size_t)t * NN;
  for (int j = 0; j < NN; ++j) acc += srow[j] * WoT[(N_IN + j) * N_OUT + o];
  out[(size_t)t * N_OUT + o] = acc;
}

// ---------------------------------------------------------------------------
extern "C" void kernel_launch(void* const* d_in, const int* in_sizes, int n_in,
                              void* d_out, int out_size, void* d_ws, size_t ws_size,
                              hipStream_t stream) {
  const float* X     = (const float*)d_in[0];
  const float* y     = (const float*)d_in[1];
  const float* W_in  = (const float*)d_in[2];
  const float* W_res = (const float*)d_in[3];
  const float* W_fb  = (const float*)d_in[4];
  const float* W_out = (const float*)d_in[5];
  const float* b     = (const float*)d_in[6];
  float* out = (float*)d_out;

  // workspace layout (float offsets):
  //   drive : [2048][4000]        at 0            (8,192,000)
  //   states: [2048][4000]        at 8,192,000    (8,192,000)
  //   WoT   : [4032][32]          at 16,384,000   (129,024)
  //   tags  : [250][16] u32       at 16,513,024   (4,000 -> pad 4,096)
  float* ws = (float*)d_ws;
  float* drive    = ws;
  float* states   = ws + 8192000;
  float* WoT      = ws + 16384000;
  unsigned* tags  = (unsigned*)(ws + 16513024);

  hipMemsetAsync(tags, 0, 4096 * sizeof(unsigned), stream);
  drive_kernel<<<dim3(16, T_STEPS), TPB, 0, stream>>>(X, y, W_in, W_fb, b, drive);
  transpose_wout_kernel<<<(N_OUT * NEXT + TPB - 1) / TPB, TPB, 0, stream>>>(W_out, WoT);
  esn_scan_kernel<<<NWG, TPB, 0, stream>>>(W_res, drive, states, tags);
  out_kernel<<<T_STEPS / 8, TPB, 0, stream>>>(X, states, WoT, out);
}